// Round 6
// baseline (279.653 us; speedup 1.0000x reference)
//
#include <hip/hip_runtime.h>
#include <hip/hip_bf16.h>

// GegenbauerKAN == GEMM y[b,o] = sum_k G[b,k]*W[k,o], M=16384 N=512 K=4096.
// ALPHA=1 => Chebyshev-U: C_{n+1} = 2t*C_n - C_{n-1}, t = tanh(x).
// R6 == R5 with the conversion spelled via __float22bfloat162_rn (union copy)
// -- __builtin_amdgcn_cvt_pk_bf16_f32 doesn't exist on this ROCm, and R3
// already proved this spelling compiles and is cheap (VALUBusy 27%).
// Structure: A-frags computed per-lane on VALU, B via double-buffered
// XOR-swizzled LDS, 2-wave blocks, unroll-2 K-loop.
// k-slot s=kc*4+fq holds i=it*8+2*fq+kc.

#define I_DIM 512
#define O_DIM 512
#define NDEG 8
#define KIT 64

typedef short s8v __attribute__((ext_vector_type(8)));    // MFMA A/B frag
typedef float f32x4 __attribute__((ext_vector_type(4)));  // MFMA C/D frag
typedef unsigned short u16;

__device__ __forceinline__ unsigned cvt_pk(float a, float b) {
    // lowers to v_cvt_pk_bf16_f32 on gfx950 (R3-verified cheap path)
    union { __hip_bfloat162 h; unsigned u; } c;
    c.h = __float22bfloat162_rn(make_float2(a, b));
    return c.u;
}

__device__ __forceinline__ float fast_tanh(float v) {
    float e = __expf(v + v);
    float r = __builtin_amdgcn_rcpf(e + 1.0f);
    return 1.0f - (r + r);
}

// Chebyshev-U degrees 0..7 -> one MFMA A-fragment (bf16)
__device__ __forceinline__ s8v cheb_frag(float t) {
    const float t2 = t + t;
    const float c1 = t2;
    const float c2 = t2 * c1 - 1.0f;
    const float c3 = t2 * c2 - c1;
    const float c4 = t2 * c3 - c2;
    const float c5 = t2 * c4 - c3;
    const float c6 = t2 * c5 - c4;
    const float c7 = t2 * c6 - c5;
    union { s8v s; unsigned u[4]; } pk;
    pk.u[0] = cvt_pk(1.0f, c1);
    pk.u[1] = cvt_pk(c2, c3);
    pk.u[2] = cvt_pk(c4, c5);
    pk.u[3] = cvt_pk(c6, c7);
    return pk.s;
}

__global__ __launch_bounds__(128, 2)
void gegen_gemm(const float* __restrict__ x,
                const float* __restrict__ cf,
                float* __restrict__ out)
{
    // B tile: 64 o-rows x 64 k, bf16, double-buffered, XOR-swizzled granules:
    // logical k-granule g of row o lives at granule slot g^(o&7).
    __shared__ u16 Ws[2][64 * 64];

    const int tid  = threadIdx.x;
    const int lane = tid & 63;
    const int wave = tid >> 6;            // 0..1, stacked in M
    const int fm   = lane & 15;
    const int fq   = lane >> 4;

    const int m0 = blockIdx.y * 128 + wave * 64;
    const int n0 = blockIdx.x * 64;

    // ---- W staging map: thread -> logical slot s (k-granule), 4 o-rows.
    // slot s holds i = 2*(s&3) + (s>>2)  (so chain (kc,fq) <-> slot kc*4+fq).
    const int s  = tid >> 4;              // 0..7
    const int og = (tid & 15) << 2;       // 0,4,...,60
    const int ig = 2 * (s & 3) + (s >> 2);
    const float* wp = cf + ((size_t)ig * O_DIM + n0 + og) * NDEG;  // 32 floats, contiguous

    // ---- x pointers: lane (fm,fq) -> rows m0+tm*16+fm, cols 2fq,2fq+1 (+8/iter)
    const float* xb[4];
#pragma unroll
    for (int tm = 0; tm < 4; ++tm)
        xb[tm] = x + (size_t)(m0 + tm * 16 + fm) * I_DIM + 2 * fq;

    f32x4 acc[4][4];
#pragma unroll
    for (int a = 0; a < 4; ++a)
#pragma unroll
        for (int b = 0; b < 4; ++b)
            acc[a][b] = (f32x4){0.0f, 0.0f, 0.0f, 0.0f};

    // ---- prologue loads (iter 0)
    float4 wv[8];
#pragma unroll
    for (int j = 0; j < 8; ++j)
        wv[j] = reinterpret_cast<const float4*>(wp)[j];
    float2 xv[4];
#pragma unroll
    for (int tm = 0; tm < 4; ++tm)
        xv[tm] = *reinterpret_cast<const float2*>(xb[tm]);

#pragma unroll 2
    for (int it = 0; it < KIT; ++it) {
        u16* wbuf = &Ws[it & 1][0];

        // ---- convert & store this iter's W tile (loaded last iter)
#pragma unroll
        for (int r = 0; r < 4; ++r) {
            union { s8v v; unsigned u[4]; } pk;
            pk.u[0] = cvt_pk(wv[2 * r].x, wv[2 * r].y);
            pk.u[1] = cvt_pk(wv[2 * r].z, wv[2 * r].w);
            pk.u[2] = cvt_pk(wv[2 * r + 1].x, wv[2 * r + 1].y);
            pk.u[3] = cvt_pk(wv[2 * r + 1].z, wv[2 * r + 1].w);
            const int row = og + r;
            const int p   = s ^ (row & 7);
            *reinterpret_cast<s8v*>(&wbuf[row * 64 + p * 8]) = pk.v;
        }
        __syncthreads();

        // ---- prefetch next tiles AFTER the barrier (drained only next iter,
        // hidden behind this iter's compute). Clamp instead of branch.
        const int nit = (it < KIT - 1) ? it + 1 : it;
        float4 wn[8];
        const float* wsrc = wp + (size_t)nit * (NDEG * O_DIM * NDEG);
#pragma unroll
        for (int j = 0; j < 8; ++j)
            wn[j] = reinterpret_cast<const float4*>(wsrc)[j];
        float2 xn[4];
#pragma unroll
        for (int tm = 0; tm < 4; ++tm)
            xn[tm] = *reinterpret_cast<const float2*>(xb[tm] + nit * NDEG);

        // ---- compute: chains (VALU) -> A frags; B frags from LDS; 32 MFMA
#pragma unroll
        for (int kc = 0; kc < 2; ++kc) {
            s8v afr[4];
#pragma unroll
            for (int tm = 0; tm < 4; ++tm)
                afr[tm] = cheb_frag(fast_tanh(kc ? xv[tm].y : xv[tm].x));
            s8v bfr[4];
#pragma unroll
            for (int tn = 0; tn < 4; ++tn) {
                const int row = tn * 16 + fm;
                const int p   = (kc * 4 + fq) ^ (row & 7);
                bfr[tn] = *reinterpret_cast<const s8v*>(&wbuf[row * 64 + p * 8]);
            }
#pragma unroll
            for (int tm = 0; tm < 4; ++tm)
#pragma unroll
                for (int tn = 0; tn < 4; ++tn)
                    acc[tm][tn] = __builtin_amdgcn_mfma_f32_16x16x32_bf16(
                        afr[tm], bfr[tn], acc[tm][tn], 0, 0, 0);
        }

#pragma unroll
        for (int j = 0; j < 8; ++j) wv[j] = wn[j];
#pragma unroll
        for (int tm = 0; tm < 4; ++tm) xv[tm] = xn[tm];
    }

    // ---- epilogue: C/D col=fm, row=fq*4+r (verified layout)
#pragma unroll
    for (int tm = 0; tm < 4; ++tm)
#pragma unroll
        for (int tn = 0; tn < 4; ++tn) {
            const int row = m0 + tm * 16 + fq * 4;
            const int col = n0 + tn * 16 + fm;
#pragma unroll
            for (int r = 0; r < 4; ++r)
                out[(size_t)(row + r) * O_DIM + col] = acc[tm][tn][r];
        }
}

extern "C" void kernel_launch(void* const* d_in, const int* in_sizes, int n_in,
                              void* d_out, int out_size, void* d_ws, size_t ws_size,
                              hipStream_t stream) {
    const float* x  = (const float*)d_in[0];
    const float* cf = (const float*)d_in[1];
    float* out = (float*)d_out;
    const int M = in_sizes[0] / I_DIM;              // 16384
    // grid.x = 8 == XCD count: all blocks on an XCD share one W n-slice (L2-resident)
    dim3 grid(O_DIM / 64, M / 128);                 // (8, 128) = 1024 blocks
    gegen_gemm<<<grid, dim3(128, 1, 1), 0, stream>>>(x, cf, out);
}

// Round 7
// 186.582 us; speedup vs baseline: 1.4988x; 1.4988x over previous
//
#include <hip/hip_runtime.h>
#include <hip/hip_bf16.h>

// GegenbauerKAN == GEMM y[b,o] = sum_k G[b,k]*W[k,o], M=16384 N=512 K=4096.
// ALPHA=1 => Chebyshev-U: C_{n+1} = 2t*C_n - C_{n-1}, t = tanh(x).
// R7: A-frags computed per-lane in registers with CHEAP bf16 pack
// (v_add+v_perm half-up round, 3 ops/pair vs ~10 for RNE -- R3/R4/R6 showed
// chains at ~130 cyc dominated by the pack). B-only LDS in a LINEAR granule
// layout (granule (g,n) at (g*64+n)*16B): writes and reads are contiguous
// runs -> zero bank conflicts by construction. Double-buffered, 1 barrier/it.
// Block: 4 waves stacked in M (BM=256, BN=64), grid (8,64)=512 -> 2 blocks/CU.
// k-convention (matches R4/R6 passing runs): k-group s=kc*4+fq holds
// i = it*8 + 2*fq + kc; degrees d=0..7 inner.

#define I_DIM 512
#define O_DIM 512
#define NDEG 8
#define KIT 64

typedef short s8v __attribute__((ext_vector_type(8)));    // MFMA A/B frag
typedef float f32x4 __attribute__((ext_vector_type(4)));  // MFMA C/D frag
typedef unsigned short u16;

// pack two fp32 -> packed bf16 pair (a low, b high), round-half-up:
// bias 0x8000 then take high 16 bits via one v_perm_b32.
__device__ __forceinline__ unsigned pack_bf(float a, float b) {
    unsigned ua = __float_as_uint(a) + 0x8000u;
    unsigned ub = __float_as_uint(b) + 0x8000u;
#if __has_builtin(__builtin_amdgcn_perm)
    return __builtin_amdgcn_perm(ub, ua, 0x07060302u);  // [ub.b3 ub.b2 ua.b3 ua.b2]
#else
    return (ua >> 16) | (ub & 0xffff0000u);
#endif
}

__device__ __forceinline__ float fast_tanh(float v) {
    float e = __expf(v + v);
    float r = __builtin_amdgcn_rcpf(e + 1.0f);
    return 1.0f - (r + r);
}

// Chebyshev-U degrees 0..7 of t -> one MFMA A-fragment (bf16)
__device__ __forceinline__ s8v cheb_frag(float t) {
    const float t2 = t + t;
    const float c1 = t2;
    const float c2 = t2 * c1 - 1.0f;
    const float c3 = t2 * c2 - c1;
    const float c4 = t2 * c3 - c2;
    const float c5 = t2 * c4 - c3;
    const float c6 = t2 * c5 - c4;
    const float c7 = t2 * c6 - c5;
    union { s8v s; unsigned u[4]; } pk;
    pk.u[0] = pack_bf(1.0f, c1);
    pk.u[1] = pack_bf(c2, c3);
    pk.u[2] = pack_bf(c4, c5);
    pk.u[3] = pack_bf(c6, c7);
    return pk.s;
}

__global__ __launch_bounds__(256, 2)
void gegen_gemm(const float* __restrict__ x,
                const float* __restrict__ cf,
                float* __restrict__ out)
{
    // B tile: granule (g 0..7, n 0..63) = 16B holding degrees 0..7 of
    // i = 2*(g&3)+(g>>2) for column n0+n.  Linear: addr = (g*64+n)*16B.
    __shared__ u16 Bs[2][8 * 64 * NDEG];   // 2 x 8 KiB

    const int tid  = threadIdx.x;
    const int lane = tid & 63;
    const int wave = tid >> 6;            // 0..3, stacked in M
    const int fm   = lane & 15;
    const int fq   = lane >> 4;

    const int m0 = blockIdx.y * 256 + wave * 64;
    const int n0 = blockIdx.x * 64;

    // ---- B staging: thread t -> granules (g, np), (g, np+1); src 64B contig
    const int g  = tid >> 5;              // 0..7
    const int np = (tid & 31) * 2;        // 0,2,..,62
    const int ig = 2 * (g & 3) + (g >> 2);
    const float* wp = cf + ((size_t)ig * O_DIM + n0 + np) * NDEG;  // 16 floats
    const int soff = (g * 64 + np) * NDEG;                         // u16 index

    // ---- x: lane (fm,fq) needs cols it*8 + 2fq (+1) of 4 rows
    const float* xr[4];
#pragma unroll
    for (int tm = 0; tm < 4; ++tm)
        xr[tm] = x + (size_t)(m0 + tm * 16 + fm) * I_DIM + 2 * fq;

    f32x4 acc[4][4];
#pragma unroll
    for (int a = 0; a < 4; ++a)
#pragma unroll
        for (int b = 0; b < 4; ++b)
            acc[a][b] = (f32x4){0.0f, 0.0f, 0.0f, 0.0f};

    // ---- prologue: load + stage B(0), load x(0)
    {
        float4 w0 = reinterpret_cast<const float4*>(wp)[0];
        float4 w1 = reinterpret_cast<const float4*>(wp)[1];
        float4 w2 = reinterpret_cast<const float4*>(wp)[2];
        float4 w3 = reinterpret_cast<const float4*>(wp)[3];
        union { s8v s; unsigned u[4]; } p0, p1;
        p0.u[0] = pack_bf(w0.x, w0.y); p0.u[1] = pack_bf(w0.z, w0.w);
        p0.u[2] = pack_bf(w1.x, w1.y); p0.u[3] = pack_bf(w1.z, w1.w);
        p1.u[0] = pack_bf(w2.x, w2.y); p1.u[1] = pack_bf(w2.z, w2.w);
        p1.u[2] = pack_bf(w3.x, w3.y); p1.u[3] = pack_bf(w3.z, w3.w);
        reinterpret_cast<s8v*>(&Bs[0][soff])[0] = p0.s;
        reinterpret_cast<s8v*>(&Bs[0][soff])[1] = p1.s;
    }
    float2 xv[4];
#pragma unroll
    for (int tm = 0; tm < 4; ++tm)
        xv[tm] = *reinterpret_cast<const float2*>(xr[tm]);
    __syncthreads();

#pragma unroll 2
    for (int it = 0; it < KIT; ++it) {
        const u16* bbuf = &Bs[it & 1][0];

        // ---- prefetch it+1 (clamped; issued before compute so latency is
        // covered by this iter's chains+MFMA)
        const int nit = (it < KIT - 1) ? it + 1 : it;
        const float* wsrc = wp + (size_t)nit * (NDEG * O_DIM * NDEG);
        float4 w0 = reinterpret_cast<const float4*>(wsrc)[0];
        float4 w1 = reinterpret_cast<const float4*>(wsrc)[1];
        float4 w2 = reinterpret_cast<const float4*>(wsrc)[2];
        float4 w3 = reinterpret_cast<const float4*>(wsrc)[3];
        float2 xn[4];
#pragma unroll
        for (int tm = 0; tm < 4; ++tm)
            xn[tm] = *reinterpret_cast<const float2*>(xr[tm] + nit * NDEG);

        // ---- compute iter it
#pragma unroll
        for (int kc = 0; kc < 2; ++kc) {
            s8v bfr[4];
#pragma unroll
            for (int tn = 0; tn < 4; ++tn)
                bfr[tn] = *reinterpret_cast<const s8v*>(
                    &bbuf[((kc * 4 + fq) * 64 + tn * 16 + fm) * NDEG]);
            s8v afr[4];
#pragma unroll
            for (int tm = 0; tm < 4; ++tm)
                afr[tm] = cheb_frag(fast_tanh(kc ? xv[tm].y : xv[tm].x));
#pragma unroll
            for (int tm = 0; tm < 4; ++tm)
#pragma unroll
                for (int tn = 0; tn < 4; ++tn)
                    acc[tm][tn] = __builtin_amdgcn_mfma_f32_16x16x32_bf16(
                        afr[tm], bfr[tn], acc[tm][tn], 0, 0, 0);
        }

        // ---- stage B(it+1) into the other buffer, then one barrier
        {
            u16* nb = &Bs[(it + 1) & 1][soff];
            union { s8v s; unsigned u[4]; } p0, p1;
            p0.u[0] = pack_bf(w0.x, w0.y); p0.u[1] = pack_bf(w0.z, w0.w);
            p0.u[2] = pack_bf(w1.x, w1.y); p0.u[3] = pack_bf(w1.z, w1.w);
            p1.u[0] = pack_bf(w2.x, w2.y); p1.u[1] = pack_bf(w2.z, w2.w);
            p1.u[2] = pack_bf(w3.x, w3.y); p1.u[3] = pack_bf(w3.z, w3.w);
            reinterpret_cast<s8v*>(nb)[0] = p0.s;
            reinterpret_cast<s8v*>(nb)[1] = p1.s;
        }
        __syncthreads();

#pragma unroll
        for (int tm = 0; tm < 4; ++tm) xv[tm] = xn[tm];
    }

    // ---- epilogue: C/D col=fm, row=fq*4+r (verified layout)
#pragma unroll
    for (int tm = 0; tm < 4; ++tm)
#pragma unroll
        for (int tn = 0; tn < 4; ++tn) {
            const int row = m0 + tm * 16 + fq * 4;
            const int col = n0 + tn * 16 + fm;
#pragma unroll
            for (int r = 0; r < 4; ++r)
                out[(size_t)(row + r) * O_DIM + col] = acc[tm][tn][r];
        }
}

extern "C" void kernel_launch(void* const* d_in, const int* in_sizes, int n_in,
                              void* d_out, int out_size, void* d_ws, size_t ws_size,
                              hipStream_t stream) {
    const float* x  = (const float*)d_in[0];
    const float* cf = (const float*)d_in[1];
    float* out = (float*)d_out;
    const int M = in_sizes[0] / I_DIM;              // 16384
    // grid.x = 8 == XCD count: blocks on an XCD share one 1 MB W n-slice (L2)
    dim3 grid(O_DIM / 64, M / 256);                 // (8, 64) = 512 blocks
    gegen_gemm<<<grid, dim3(256, 1, 1), 0, stream>>>(x, cf, out);
}